// Round 16
// baseline (177.134 us; speedup 1.0000x reference)
//
#include <hip/hip_runtime.h>
#include <hip/hip_bf16.h>

typedef unsigned short u16;
typedef __bf16 bf16x8 __attribute__((ext_vector_type(8)));
typedef float f32x4 __attribute__((ext_vector_type(4)));
typedef unsigned short u16x8 __attribute__((ext_vector_type(8)));
typedef unsigned short u16x4 __attribute__((ext_vector_type(4)));

__device__ __forceinline__ float bf2f(u16 u) {
  unsigned int x = ((unsigned int)u) << 16;
  return __builtin_bit_cast(float, x);
}
__device__ __forceinline__ u16 f2bf(float f) {
  unsigned int x = __builtin_bit_cast(unsigned int, f);
  x = x + 0x7FFFu + ((x >> 16) & 1u);
  return (u16)(x >> 16);
}

// async global->LDS, 16B per lane; LDS dest is wave-uniform base + lane*16.
__device__ __forceinline__ void gload_lds16(const u16* g, u16* l) {
  __builtin_amdgcn_global_load_lds(
      (const __attribute__((address_space(1))) unsigned int*)(unsigned long long)(uintptr_t)g,
      (__attribute__((address_space(3))) unsigned int*)(unsigned int)(uintptr_t)l,
      16, 0, 0);
}

// ---------------- prep (r16): cast X + transpose Wv only ----------------
// (W q/k casts moved into gemm_g, which reads fp32 directly -> prep and G
// are independent dispatches and overlap on the GPU.)
__global__ __launch_bounds__(256) void prep_kernel(const float* __restrict__ X,
                                                   const float* __restrict__ Wv,
                                                   u16* __restrict__ Xb,
                                                   u16* __restrict__ Wvt) {
  const int id = blockIdx.x;
  const int tid = threadIdx.x;
  if (id < 4096) {
    long i = ((long)id * 256 + tid) * 8;
    float4 a = *reinterpret_cast<const float4*>(X + i);
    float4 b = *reinterpret_cast<const float4*>(X + i + 4);
    u16x8 o;
    o[0] = f2bf(a.x); o[1] = f2bf(a.y); o[2] = f2bf(a.z); o[3] = f2bf(a.w);
    o[4] = f2bf(b.x); o[5] = f2bf(b.y); o[6] = f2bf(b.z); o[7] = f2bf(b.w);
    *reinterpret_cast<u16x8*>(Xb + i) = o;
    return;
  }
  __shared__ u16 t[64][72];
  const int id2 = id - 4096;          // 0..255
  const int c0 = (id2 & 15) * 64;
  const int r0 = (id2 >> 4) * 64;
#pragma unroll
  for (int i = 0; i < 4; ++i) {
    int slot = tid + 256 * i;
    int lr = slot >> 4;
    int lc4 = slot & 15;
    float4 v = *reinterpret_cast<const float4*>(Wv + (long)(r0 + lr) * 1024 + c0 + lc4 * 4);
    t[lr][lc4 * 4 + 0] = f2bf(v.x);
    t[lr][lc4 * 4 + 1] = f2bf(v.y);
    t[lr][lc4 * 4 + 2] = f2bf(v.z);
    t[lr][lc4 * 4 + 3] = f2bf(v.w);
  }
  __syncthreads();
#pragma unroll
  for (int i = 0; i < 2; ++i) {
    int slot = tid + 256 * i;
    int orow = slot >> 3;
    int oc = slot & 7;
    u16x8 o;
#pragma unroll
    for (int j = 0; j < 8; ++j) o[j] = t[oc * 8 + j][orow];
    *reinterpret_cast<u16x8*>(Wvt + (long)(c0 + orow) * 1024 + r0 + oc * 8) = o;
  }
}

// ---------------- G = M^T: Gt[d'][d] = Sum_e Wk[d',e] Wq[d,e] / 32 ----------------
// SELF-CASTING: reads fp32 Wk (A) and Wq (B, scaled 1/32) directly; reg-stage
// with in-register cvt + XOR-swizzled ds_write_b128 (r1-proven, 0 conflicts).
// 64 blocks of 128x128, 4 waves of 64x64, BK=64, single-buffer 2-barrier loop
// (G is tiny and overlapped with prep; simplicity > peak here).
__global__ __launch_bounds__(256, 2) void gemm_g(const float* __restrict__ Wk,
                                                 const float* __restrict__ Wq,
                                                 u16* __restrict__ Gt) {
  const int bm = blockIdx.x >> 3;       // 0..7  (d' tile)
  const int bn = blockIdx.x & 7;        // 0..7  (d tile)
  const int m0 = bm * 128, n0 = bn * 128;

  __shared__ u16 ldsA[8192];            // 128 x 64
  __shared__ u16 ldsB[8192];

  const int tid = threadIdx.x;
  const int lane = tid & 63;
  const int wid = tid >> 6;
  const int wm = wid >> 1, wn = wid & 1;
  const int l16 = lane & 15, lh = lane >> 4;
  const int csl = tid & 7;              // 8-elem column slot
  const int rbase = tid >> 3;           // 0..31

  f32x4 acc[4][4];
#pragma unroll
  for (int mi = 0; mi < 4; ++mi)
#pragma unroll
    for (int ni = 0; ni < 4; ++ni) acc[mi][ni] = (f32x4)(0.0f);

  for (int k0 = 0; k0 < 1024; k0 += 64) {
    __syncthreads();                    // previous compute's reads done
#pragma unroll
    for (int c = 0; c < 4; ++c) {
      const int row = c * 32 + rbase;   // 0..127
      const int sp = (csl ^ (row & 7)) * 8;
      float4 a0 = *reinterpret_cast<const float4*>(Wk + (long)(m0 + row) * 1024 + k0 + csl * 8);
      float4 a1 = *reinterpret_cast<const float4*>(Wk + (long)(m0 + row) * 1024 + k0 + csl * 8 + 4);
      u16x8 oa;
      oa[0] = f2bf(a0.x); oa[1] = f2bf(a0.y); oa[2] = f2bf(a0.z); oa[3] = f2bf(a0.w);
      oa[4] = f2bf(a1.x); oa[5] = f2bf(a1.y); oa[6] = f2bf(a1.z); oa[7] = f2bf(a1.w);
      *reinterpret_cast<u16x8*>(&ldsA[row * 64 + sp]) = oa;
      float4 b0 = *reinterpret_cast<const float4*>(Wq + (long)(n0 + row) * 1024 + k0 + csl * 8);
      float4 b1 = *reinterpret_cast<const float4*>(Wq + (long)(n0 + row) * 1024 + k0 + csl * 8 + 4);
      u16x8 ob;
      const float s = 1.0f / 32.0f;
      ob[0] = f2bf(b0.x * s); ob[1] = f2bf(b0.y * s); ob[2] = f2bf(b0.z * s); ob[3] = f2bf(b0.w * s);
      ob[4] = f2bf(b1.x * s); ob[5] = f2bf(b1.y * s); ob[6] = f2bf(b1.z * s); ob[7] = f2bf(b1.w * s);
      *reinterpret_cast<u16x8*>(&ldsB[row * 64 + sp]) = ob;
    }
    __syncthreads();                    // writes visible
#pragma unroll
    for (int kk = 0; kk < 2; ++kk) {
      bf16x8 af[4], bfr[4];
#pragma unroll
      for (int mi = 0; mi < 4; ++mi) {
        const int row = wm * 64 + mi * 16 + l16;
        af[mi] = *reinterpret_cast<const bf16x8*>(
            &ldsA[row * 64 + (((kk * 4 + lh) ^ (row & 7))) * 8]);
      }
#pragma unroll
      for (int ni = 0; ni < 4; ++ni) {
        const int row = wn * 64 + ni * 16 + l16;
        bfr[ni] = *reinterpret_cast<const bf16x8*>(
            &ldsB[row * 64 + (((kk * 4 + lh) ^ (row & 7))) * 8]);
      }
#pragma unroll
      for (int mi = 0; mi < 4; ++mi)
#pragma unroll
        for (int ni = 0; ni < 4; ++ni)
          acc[mi][ni] = __builtin_amdgcn_mfma_f32_16x16x32_bf16(bfr[ni], af[mi], acc[mi][ni], 0, 0, 0);
    }
  }

  // Swapped: Gt[m0+wm*64+mi*16+l16][n0+wn*64+ni*16+lh*4+r]
  const long rown = (long)(m0 + wm * 64 + l16);
  const int coln = n0 + wn * 64 + lh * 4;
#pragma unroll
  for (int mi = 0; mi < 4; ++mi)
#pragma unroll
    for (int ni = 0; ni < 4; ++ni) {
      u16x4 o;
#pragma unroll
      for (int r = 0; r < 4; ++r) o[r] = f2bf(acc[mi][ni][r]);
      *reinterpret_cast<u16x4*>(&Gt[(rown + mi * 16) * 1024 + coln + ni * 16]) = o;
    }
}

// ---------------- [T1|V] = NT(Xb, [Gt;Wvt]): 64x256 tile, 8 waves (r16) ----------
// r15 T1V ran the 4-wave 128^2 kernel (708 TF). r11 proved 8-wave/80KB/2-per-CU
// = 873 TF; 192 doesn't divide N=2048, so use 64x256 (M+N=320 -> same 80KB).
// 8 waves of 32x64 (acc[2][4]; 21.3 FLOP/LDS-B -> 1.47 PF LDS ceiling).
// Grid 128x8 = 1024 = exactly 2.0 rounds. bn<4 -> T1 (swapped epilogue);
// bn>=4 -> V, normal order, transposed store to Vt[b][e][t].
// Same proven loop: BK=64, dbuf, one __syncthreads/K-step, stage-after-barrier.
__global__ __launch_bounds__(512, 4) void gemm_t1v(const u16* __restrict__ Xb,
                                                   const u16* __restrict__ WG,
                                                   u16* __restrict__ T1,
                                                   u16* __restrict__ Vt) {
  const int id = blockIdx.x;            // 0..1023
  const int xcd = id & 7, j = id >> 3;  // j: 0..127
  const int bn = (xcd & 1) * 4 + (j & 3);        // 0..7
  const int bm = ((xcd >> 1) << 5) + (j >> 2);   // 0..127
  const int m0 = bm * 64, n0 = bn * 256;
  const int K = 1024;

  __shared__ u16 ldsA[2][4096];    // 64 x 64
  __shared__ u16 ldsB[2][16384];   // 256 x 64

  const int tid = threadIdx.x;          // 0..511
  const int lane = tid & 63;
  const int wid = tid >> 6;             // 0..7
  const int wm = wid >> 2, wn = wid & 3;
  const int l16 = lane & 15, lh = lane >> 4;
  const int strow = tid >> 3;                       // 0..63
  const int scol = ((tid & 7) ^ (strow & 7)) * 8;   // pre-swizzled source col
  const int rsw = l16 & 7;                          // read-side swizzle key

  const bool vblk = (bn >= 4);

  f32x4 acc[2][4];
#pragma unroll
  for (int mi = 0; mi < 2; ++mi)
#pragma unroll
    for (int ni = 0; ni < 4; ++ni) acc[mi][ni] = (f32x4)(0.0f);

  auto stage = [&](int d, int k0) {
    gload_lds16(Xb + (long)(m0 + strow) * K + k0 + scol, &ldsA[d][tid * 8]);
#pragma unroll
    for (int l = 0; l < 4; ++l)
      gload_lds16(WG + (long)(n0 + l * 64 + strow) * K + k0 + scol,
                  &ldsB[d][l * 4096 + tid * 8]);
  };

  stage(0, 0);
  int cur = 0;
  for (int k0 = 0; k0 < K; k0 += 64) {
    __syncthreads();                          // buf[cur] ready; old readers done
    if (k0 + 64 < K) stage(cur ^ 1, k0 + 64); // lands during compute below
#pragma unroll
    for (int kk = 0; kk < 2; ++kk) {
      bf16x8 af[2], bfr[4];
#pragma unroll
      for (int mi = 0; mi < 2; ++mi) {
        const int row = wm * 32 + mi * 16 + l16;
        af[mi] = *reinterpret_cast<const bf16x8*>(
            &ldsA[cur][row * 64 + (((kk * 4 + lh) ^ rsw)) * 8]);
      }
#pragma unroll
      for (int ni = 0; ni < 4; ++ni) {
        const int row = wn * 64 + ni * 16 + l16;
        bfr[ni] = *reinterpret_cast<const bf16x8*>(
            &ldsB[cur][row * 64 + (((kk * 4 + lh) ^ rsw)) * 8]);
      }
      if (!vblk) {
#pragma unroll
        for (int mi = 0; mi < 2; ++mi)
#pragma unroll
          for (int ni = 0; ni < 4; ++ni)
            acc[mi][ni] = __builtin_amdgcn_mfma_f32_16x16x32_bf16(bfr[ni], af[mi], acc[mi][ni], 0, 0, 0);
      } else {
#pragma unroll
        for (int mi = 0; mi < 2; ++mi)
#pragma unroll
          for (int ni = 0; ni < 4; ++ni)
            acc[mi][ni] = __builtin_amdgcn_mfma_f32_16x16x32_bf16(af[mi], bfr[ni], acc[mi][ni], 0, 0, 0);
      }
    }
    cur ^= 1;
  }

  if (!vblk) {
    // Swapped: T1[m0+wm*32+mi*16+l16][bn*256+wn*64+ni*16+lh*4+r]
    const long rown = (long)(m0 + wm * 32 + l16);
    const int coln = bn * 256 + wn * 64 + lh * 4;
#pragma unroll
    for (int mi = 0; mi < 2; ++mi)
#pragma unroll
      for (int ni = 0; ni < 4; ++ni) {
        u16x4 o;
#pragma unroll
        for (int r = 0; r < 4; ++r) o[r] = f2bf(acc[mi][ni][r]);
        *reinterpret_cast<u16x4*>(&T1[(rown + mi * 16) * 1024 + coln + ni * 16]) = o;
      }
  } else {
    // V (normal order): D row = M-dim(t). Vt[b][e][t], vector along t.
    const int b = m0 >> 11;
    const int t0 = (m0 & 2047) + wm * 32 + lh * 4;
    const int e0 = (bn - 4) * 256 + wn * 64 + l16;
#pragma unroll
    for (int mi = 0; mi < 2; ++mi)
#pragma unroll
      for (int ni = 0; ni < 4; ++ni) {
        u16x4 o;
#pragma unroll
        for (int r = 0; r < 4; ++r) o[r] = f2bf(acc[mi][ni][r]);
        *reinterpret_cast<u16x4*>(
            &Vt[(long)b * 2097152 + (long)(e0 + ni * 16) * 2048 + t0 + mi * 16]) = o;
      }
  }
}

// ---------------- S = exp(T1 X^T): 64x128 tiles, BK=64, 3/CU (r13, unchanged) -----
__global__ __launch_bounds__(256, 3) void gemm_s(const u16* __restrict__ T1,
                                                 const u16* __restrict__ Xb,
                                                 u16* __restrict__ Sg,
                                                 float* __restrict__ Sums) {
  const int id = blockIdx.x;            // 0..1087
  const int x = id & 7;                 // XCD (round-robin assumption)
  const int q = id >> 3;                // 0..135
  const int bz = q / 34;
  int u = q - bz * 34;
  int qr, kc;
  const int n1 = 32 - 2 * x;            // tiles with kc = x  (qr = 2x..31)
  if (u < n1) { kc = x;      qr = 2 * x + u; }
  else        { kc = 15 - x; qr = 30 - 2 * x + (u - n1); }
  const int m0 = qr * 64, n0 = kc * 128;
  const int K = 1024;

  const u16* A = T1 + (long)bz * 2097152;
  const u16* B = Xb + (long)bz * 2097152;

  __shared__ u16 ldsA[2][4096];    // 64 x 64
  __shared__ u16 ldsB[2][8192];    // 128 x 64

  const int tid = threadIdx.x;          // 0..255
  const int lane = tid & 63;
  const int wn = tid >> 6;              // wave 0..3 owns cols wn*32..wn*32+31
  const int l16 = lane & 15, lh = lane >> 4;
  const int strow = tid >> 3;                       // 0..31
  const int scol = ((tid & 7) ^ (strow & 7)) * 8;   // pre-swizzled source col
  const int rsw = l16 & 7;                          // read-side swizzle key

  f32x4 acc[4][2];
#pragma unroll
  for (int mi = 0; mi < 4; ++mi)
#pragma unroll
    for (int ni = 0; ni < 2; ++ni) acc[mi][ni] = (f32x4)(0.0f);

  auto stage = [&](int d, int k0) {
#pragma unroll
    for (int l = 0; l < 2; ++l)
      gload_lds16(A + (long)(m0 + l * 32 + strow) * K + k0 + scol,
                  &ldsA[d][l * 2048 + tid * 8]);
#pragma unroll
    for (int l = 0; l < 4; ++l)
      gload_lds16(B + (long)(n0 + l * 32 + strow) * K + k0 + scol,
                  &ldsB[d][l * 2048 + tid * 8]);
  };

  stage(0, 0);
  int cur = 0;
  for (int k0 = 0; k0 < K; k0 += 64) {
    __syncthreads();
    if (k0 + 64 < K) stage(cur ^ 1, k0 + 64);
#pragma unroll
    for (int kk = 0; kk < 2; ++kk) {
      bf16x8 af[4], bfr[2];
#pragma unroll
      for (int mi = 0; mi < 4; ++mi)
        af[mi] = *reinterpret_cast<const bf16x8*>(
            &ldsA[cur][(mi * 16 + l16) * 64 + (((kk * 4 + lh) ^ rsw)) * 8]);
#pragma unroll
      for (int ni = 0; ni < 2; ++ni)
        bfr[ni] = *reinterpret_cast<const bf16x8*>(
            &ldsB[cur][(wn * 32 + ni * 16 + l16) * 64 + (((kk * 4 + lh) ^ rsw)) * 8]);
#pragma unroll
      for (int mi = 0; mi < 4; ++mi)
#pragma unroll
        for (int ni = 0; ni < 2; ++ni)
          acc[mi][ni] = __builtin_amdgcn_mfma_f32_16x16x32_bf16(bfr[ni], af[mi], acc[mi][ni], 0, 0, 0);
    }
    cur ^= 1;
  }

  // P = exp(S), zero above diagonal; row sums from bf16-rounded values.
  u16* C = Sg + (long)bz * 4194304;
  float* sums = Sums + (long)bz * 2048;
  const int coln = n0 + wn * 32 + lh * 4;
#pragma unroll
  for (int mi = 0; mi < 4; ++mi) {
    const int gr = m0 + mi * 16 + l16;
    float rs = 0.0f;
#pragma unroll
    for (int ni = 0; ni < 2; ++ni) {
      u16x4 o;
#pragma unroll
      for (int r = 0; r < 4; ++r) {
        const int gc = coln + ni * 16 + r;
        const float e = (gc <= gr) ? __expf(acc[mi][ni][r]) : 0.0f;
        const u16 ub = f2bf(e);
        o[r] = ub;
        rs += bf2f(ub);
      }
      *reinterpret_cast<u16x4*>(&C[(long)gr * 2048 + coln + ni * 16]) = o;
    }
    rs += __shfl_xor(rs, 16);
    rs += __shfl_xor(rs, 32);
    if (lh == 0) atomicAdd(&sums[gr], rs);
  }
}

// ---------------- PV GEMM: 128x128, 8 waves, balanced pairing (r13, unchanged) ----
__global__ __launch_bounds__(512, 2) void gemm_pv(const u16* __restrict__ Ag,
                                                  const u16* __restrict__ Bg,
                                                  float* __restrict__ Cg,
                                                  const float* __restrict__ Sums) {
  const int id = blockIdx.x;            // 0..511
  const int x = id & 7;                 // XCD; also bn
  const int q = id >> 3;                // 0..63
  const int f = (q ^ (q >> 5)) & 1;
  const int i5 = ((q >> 1) & 15) | (((q >> 5) & 1) << 4);
  const int bmb = i5 & 7;
  const int bz = (i5 >> 3) & 3;
  const int bm = f ? (15 - bmb) : bmb;
  const int bn = x;
  const int K = 2048;

  const u16* A = Ag + (long)bz * 4194304;
  const u16* B = Bg + (long)bz * 2097152;
  const int m0 = bm * 128, n0 = bn * 128;
  const int kEnd = m0 + 128;

  __shared__ u16 ldsA[2][8192];
  __shared__ u16 ldsB[2][8192];

  const int tid = threadIdx.x;          // 0..511
  const int lane = tid & 63;
  const int wid = tid >> 6;             // 0..7
  const int wm = wid >> 2, wn = wid & 3;
  const int l16 = lane & 15, lh = lane >> 4;
  const int strow = tid >> 3;                       // 0..63
  const int scol = ((tid & 7) ^ (strow & 7)) * 8;   // pre-swizzled source column
  const int rsw = l16 & 7;                          // read-side swizzle key

  f32x4 acc[4][2];
#pragma unroll
  for (int mi = 0; mi < 4; ++mi)
#pragma unroll
    for (int ni = 0; ni < 2; ++ni) acc[mi][ni] = (f32x4)(0.0f);

  auto stage = [&](int d, int k0) {
#pragma unroll
    for (int l = 0; l < 2; ++l) {
      const int row = l * 64 + strow;   // 0..127
      gload_lds16(A + (long)(m0 + row) * K + k0 + scol, &ldsA[d][l * 4096 + tid * 8]);
      gload_lds16(B + (long)(n0 + row) * K + k0 + scol, &ldsB[d][l * 4096 + tid * 8]);
    }
  };

  stage(0, 0);
  int cur = 0;
  for (int k0 = 0; k0 < kEnd; k0 += 64) {
    __syncthreads();
    if (k0 + 64 < kEnd) stage(cur ^ 1, k0 + 64);
#pragma unroll
    for (int kk = 0; kk < 2; ++kk) {
      bf16x8 af[4], bfr[2];
#pragma unroll
      for (int mi = 0; mi < 4; ++mi)
        af[mi] = *reinterpret_cast<const bf16x8*>(
            &ldsA[cur][(wm * 64 + mi * 16 + l16) * 64 + (((kk * 4 + lh) ^ rsw)) * 8]);
#pragma unroll
      for (int ni = 0; ni < 2; ++ni)
        bfr[ni] = *reinterpret_cast<const bf16x8*>(
            &ldsB[cur][(wn * 32 + ni * 16 + l16) * 64 + (((kk * 4 + lh) ^ rsw)) * 8]);
#pragma unroll
      for (int mi = 0; mi < 4; ++mi)
#pragma unroll
        for (int ni = 0; ni < 2; ++ni)
          acc[mi][ni] = __builtin_amdgcn_mfma_f32_16x16x32_bf16(bfr[ni], af[mi], acc[mi][ni], 0, 0, 0);
    }
    cur ^= 1;
  }

  // O = acc / rowsum
  float* C = Cg + (long)bz * 2097152;
  const float* sums = Sums + (long)bz * 2048;
  const long rown = (long)(m0 + wm * 64 + l16);
  const int coln = n0 + wn * 32 + lh * 4;
#pragma unroll
  for (int mi = 0; mi < 4; ++mi) {
    const float inv = 1.0f / sums[(int)rown + mi * 16];
#pragma unroll
    for (int ni = 0; ni < 2; ++ni) {
      f32x4 v = acc[mi][ni] * inv;
      *reinterpret_cast<f32x4*>(&C[(rown + mi * 16) * 1024 + coln + ni * 16]) = v;
    }
  }
}

extern "C" void kernel_launch(void* const* d_in, const int* in_sizes, int n_in,
                              void* d_out, int out_size, void* d_ws, size_t ws_size,
                              hipStream_t stream) {
  const float* X  = (const float*)d_in[0];
  const float* Wq = (const float*)d_in[1];
  const float* Wk = (const float*)d_in[2];
  const float* Wv = (const float*)d_in[3];

  // workspace layout (u16 elements)
  u16* Xb = (u16*)d_ws;                 // 8192*1024
  u16* WG = Xb + 8388608;               // [Gt; Wvt] (2M) — contiguous B for T1V
  u16* T1 = WG + 2097152;               // 8192*1024
  u16* Vt = T1 + 8388608;               // [b][1024][2048]
  u16* S  = Vt + 8388608;               // [b][2048][2048] -> holds P = exp(scores)
  float* sums = (float*)(S + 16777216); // [b][2048] row sums (32 KB)

  hipMemsetAsync(sums, 0, 4 * 2048 * sizeof(float), stream);

  // G (self-casting, independent of prep) and prep overlap on the GPU
  gemm_g<<<64, 256, 0, stream>>>(Wk, Wq, WG);
  prep_kernel<<<4352, 256, 0, stream>>>(X, Wv, Xb, WG + 1048576);

  // [T1 | V] = NT(Xb, [Gt; Wvt]) — 64x256 tile, 8 waves, 1024 blocks = 2 rounds
  gemm_t1v<<<1024, 512, 0, stream>>>(Xb, WG, T1, Vt);

  // P = exp(T1 X^T) per batch (causal zeros; row sums via atomics)
  gemm_s<<<1088, 256, 0, stream>>>(T1, Xb, S, sums);

  // O = P V / rowsum
  gemm_pv<<<512, 512, 0, stream>>>(S, Vt, (float*)d_out, sums);
}

// Round 17
// 134.812 us; speedup vs baseline: 1.3139x; 1.3139x over previous
//
#include <hip/hip_runtime.h>
#include <hip/hip_bf16.h>

typedef unsigned short u16;
typedef __bf16 bf16x8 __attribute__((ext_vector_type(8)));
typedef float f32x4 __attribute__((ext_vector_type(4)));
typedef unsigned short u16x8 __attribute__((ext_vector_type(8)));
typedef unsigned short u16x4 __attribute__((ext_vector_type(4)));

__device__ __forceinline__ float bf2f(u16 u) {
  unsigned int x = ((unsigned int)u) << 16;
  return __builtin_bit_cast(float, x);
}
__device__ __forceinline__ u16 f2bf(float f) {
  unsigned int x = __builtin_bit_cast(unsigned int, f);
  x = x + 0x7FFFu + ((x >> 16) & 1u);
  return (u16)(x >> 16);
}

// async global->LDS, 16B per lane; LDS dest is wave-uniform base + lane*16.
__device__ __forceinline__ void gload_lds16(const u16* g, u16* l) {
  __builtin_amdgcn_global_load_lds(
      (const __attribute__((address_space(1))) unsigned int*)(unsigned long long)(uintptr_t)g,
      (__attribute__((address_space(3))) unsigned int*)(unsigned int)(uintptr_t)l,
      16, 0, 0);
}

// ---------------- prep (r15 path): cast X, Wq*(1/32), Wk; transpose Wv ----------
// r16 lesson: same-stream dispatches SERIALIZE (no overlap), and a
// self-casting fp32 G was latency-bound at 65-79us. Keep W casts here (cheap,
// bandwidth-bound) and let G read bf16 with the proven dbuf kernel (~5us).
__global__ __launch_bounds__(256) void prep_kernel(const float* __restrict__ X,
                                                   const float* __restrict__ Wq,
                                                   const float* __restrict__ Wk,
                                                   const float* __restrict__ Wv,
                                                   u16* __restrict__ Xb,
                                                   u16* __restrict__ Wqr,
                                                   u16* __restrict__ Wkr,
                                                   u16* __restrict__ Wvt) {
  const int id = blockIdx.x;
  const int tid = threadIdx.x;
  if (id < 5120) {
    const float* src;
    u16* dst;
    float scale = 1.0f;
    long i;
    if (id < 4096) {
      src = X; dst = Xb; i = ((long)id * 256 + tid) * 8;
    } else if (id < 4608) {
      src = Wq; dst = Wqr; scale = 1.0f / 32.0f;   // fold 1/sqrt(1024)
      i = ((long)(id - 4096) * 256 + tid) * 8;
    } else {
      src = Wk; dst = Wkr;
      i = ((long)(id - 4608) * 256 + tid) * 8;
    }
    float4 a = *reinterpret_cast<const float4*>(src + i);
    float4 b = *reinterpret_cast<const float4*>(src + i + 4);
    u16x8 o;
    o[0] = f2bf(a.x * scale); o[1] = f2bf(a.y * scale);
    o[2] = f2bf(a.z * scale); o[3] = f2bf(a.w * scale);
    o[4] = f2bf(b.x * scale); o[5] = f2bf(b.y * scale);
    o[6] = f2bf(b.z * scale); o[7] = f2bf(b.w * scale);
    *reinterpret_cast<u16x8*>(dst + i) = o;
    return;
  }
  // Wv transpose: Wvt[c*1024 + r] = Wv[r][c]
  __shared__ u16 t[64][72];
  const int id2 = id - 5120;          // 0..255
  const int c0 = (id2 & 15) * 64;
  const int r0 = (id2 >> 4) * 64;
#pragma unroll
  for (int i = 0; i < 4; ++i) {
    int slot = tid + 256 * i;
    int lr = slot >> 4;
    int lc4 = slot & 15;
    float4 v = *reinterpret_cast<const float4*>(Wv + (long)(r0 + lr) * 1024 + c0 + lc4 * 4);
    t[lr][lc4 * 4 + 0] = f2bf(v.x);
    t[lr][lc4 * 4 + 1] = f2bf(v.y);
    t[lr][lc4 * 4 + 2] = f2bf(v.z);
    t[lr][lc4 * 4 + 3] = f2bf(v.w);
  }
  __syncthreads();
#pragma unroll
  for (int i = 0; i < 2; ++i) {
    int slot = tid + 256 * i;
    int orow = slot >> 3;
    int oc = slot & 7;
    u16x8 o;
#pragma unroll
    for (int j = 0; j < 8; ++j) o[j] = t[oc * 8 + j][orow];
    *reinterpret_cast<u16x8*>(Wvt + (long)(c0 + orow) * 1024 + r0 + oc * 8) = o;
  }
}

// ---------------- G: Gt = NT(Wkr, Wqr), 128x128, 4 waves (r15-proven) ----------
// Gt[d'][d] = Sum_e Wk[d',e] Wq[d,e]/32 = M[d,d'] — row-major, k-contig for T1V.
// BK=64, dbuf LDS, one __syncthreads per K-step, stage-after-barrier,
// gload_lds w16, pre-swizzled source + XOR-swizzled ds_read. grid 64.
__global__ __launch_bounds__(256, 2) void gemm_g(const u16* __restrict__ A,
                                                 const u16* __restrict__ B,
                                                 u16* __restrict__ Gt) {
  const int bm = blockIdx.x >> 3;       // 0..7
  const int bn = blockIdx.x & 7;
  const int m0 = bm * 128, n0 = bn * 128;
  const int K = 1024;

  __shared__ u16 ldsA[2][8192];
  __shared__ u16 ldsB[2][8192];

  const int tid = threadIdx.x;
  const int lane = tid & 63;
  const int wid = tid >> 6;
  const int wm = wid >> 1, wn = wid & 1;
  const int l16 = lane & 15, lh = lane >> 4;
  const int srow = lane >> 3;
  const int scol = ((lane & 7) ^ srow) * 8;  // pre-swizzled source column
  const int rsw = l16 & 7;                   // read-side swizzle key

  f32x4 acc[4][4];
#pragma unroll
  for (int mi = 0; mi < 4; ++mi)
#pragma unroll
    for (int ni = 0; ni < 4; ++ni) acc[mi][ni] = (f32x4)(0.0f);

  auto stage = [&](int d, int k0) {
#pragma unroll
    for (int s = 0; s < 4; ++s) {
      const int seg = wid * 4 + s;           // 0..15 (1KB segments)
      const int row = seg * 8 + srow;        // 0..127
      gload_lds16(A + (long)(m0 + row) * K + k0 + scol, &ldsA[d][seg * 512]);
      gload_lds16(B + (long)(n0 + row) * K + k0 + scol, &ldsB[d][seg * 512]);
    }
  };

  stage(0, 0);
  int cur = 0;
  for (int k0 = 0; k0 < K; k0 += 64) {
    __syncthreads();
    if (k0 + 64 < K) stage(cur ^ 1, k0 + 64);
#pragma unroll
    for (int kk = 0; kk < 2; ++kk) {
      bf16x8 af[4], bfr[4];
#pragma unroll
      for (int mi = 0; mi < 4; ++mi)
        af[mi] = *reinterpret_cast<const bf16x8*>(
            &ldsA[cur][(wm * 64 + mi * 16 + l16) * 64 + (((kk * 4 + lh) ^ rsw)) * 8]);
#pragma unroll
      for (int ni = 0; ni < 4; ++ni)
        bfr[ni] = *reinterpret_cast<const bf16x8*>(
            &ldsB[cur][(wn * 64 + ni * 16 + l16) * 64 + (((kk * 4 + lh) ^ rsw)) * 8]);
#pragma unroll
      for (int mi = 0; mi < 4; ++mi)
#pragma unroll
        for (int ni = 0; ni < 4; ++ni)
          acc[mi][ni] = __builtin_amdgcn_mfma_f32_16x16x32_bf16(bfr[ni], af[mi], acc[mi][ni], 0, 0, 0);
    }
    cur ^= 1;
  }

  // Swapped: Gt[m0+wm*64+mi*16+l16][n0+wn*64+ni*16+lh*4+r]
  const long rown = (long)(m0 + wm * 64 + l16);
  const int coln = n0 + wn * 64 + lh * 4;
#pragma unroll
  for (int mi = 0; mi < 4; ++mi)
#pragma unroll
    for (int ni = 0; ni < 4; ++ni) {
      u16x4 o;
#pragma unroll
      for (int r = 0; r < 4; ++r) o[r] = f2bf(acc[mi][ni][r]);
      *reinterpret_cast<u16x4*>(&Gt[(rown + mi * 16) * 1024 + coln + ni * 16]) = o;
    }
}

// ---------------- [T1|V] = NT(Xb, [Gt;Wvt]): 64x256 tile, 8 waves (r16, kept) ----
// Verified correct in r16 (absmax 0.0176). 8 waves of 32x64 (acc[2][4]);
// 80KB LDS -> 2 blocks/CU; grid 1024 = exactly 2.0 rounds. bn<4 -> T1
// (swapped epilogue); bn>=4 -> V, normal order, transposed to Vt[b][e][t].
__global__ __launch_bounds__(512, 4) void gemm_t1v(const u16* __restrict__ Xb,
                                                   const u16* __restrict__ WG,
                                                   u16* __restrict__ T1,
                                                   u16* __restrict__ Vt) {
  const int id = blockIdx.x;            // 0..1023
  const int xcd = id & 7, j = id >> 3;  // j: 0..127
  const int bn = (xcd & 1) * 4 + (j & 3);        // 0..7
  const int bm = ((xcd >> 1) << 5) + (j >> 2);   // 0..127
  const int m0 = bm * 64, n0 = bn * 256;
  const int K = 1024;

  __shared__ u16 ldsA[2][4096];    // 64 x 64
  __shared__ u16 ldsB[2][16384];   // 256 x 64

  const int tid = threadIdx.x;          // 0..511
  const int lane = tid & 63;
  const int wid = tid >> 6;             // 0..7
  const int wm = wid >> 2, wn = wid & 3;
  const int l16 = lane & 15, lh = lane >> 4;
  const int strow = tid >> 3;                       // 0..63
  const int scol = ((tid & 7) ^ (strow & 7)) * 8;   // pre-swizzled source col
  const int rsw = l16 & 7;                          // read-side swizzle key

  const bool vblk = (bn >= 4);

  f32x4 acc[2][4];
#pragma unroll
  for (int mi = 0; mi < 2; ++mi)
#pragma unroll
    for (int ni = 0; ni < 4; ++ni) acc[mi][ni] = (f32x4)(0.0f);

  auto stage = [&](int d, int k0) {
    gload_lds16(Xb + (long)(m0 + strow) * K + k0 + scol, &ldsA[d][tid * 8]);
#pragma unroll
    for (int l = 0; l < 4; ++l)
      gload_lds16(WG + (long)(n0 + l * 64 + strow) * K + k0 + scol,
                  &ldsB[d][l * 4096 + tid * 8]);
  };

  stage(0, 0);
  int cur = 0;
  for (int k0 = 0; k0 < K; k0 += 64) {
    __syncthreads();                          // buf[cur] ready; old readers done
    if (k0 + 64 < K) stage(cur ^ 1, k0 + 64); // lands during compute below
#pragma unroll
    for (int kk = 0; kk < 2; ++kk) {
      bf16x8 af[2], bfr[4];
#pragma unroll
      for (int mi = 0; mi < 2; ++mi) {
        const int row = wm * 32 + mi * 16 + l16;
        af[mi] = *reinterpret_cast<const bf16x8*>(
            &ldsA[cur][row * 64 + (((kk * 4 + lh) ^ rsw)) * 8]);
      }
#pragma unroll
      for (int ni = 0; ni < 4; ++ni) {
        const int row = wn * 64 + ni * 16 + l16;
        bfr[ni] = *reinterpret_cast<const bf16x8*>(
            &ldsB[cur][row * 64 + (((kk * 4 + lh) ^ rsw)) * 8]);
      }
      if (!vblk) {
#pragma unroll
        for (int mi = 0; mi < 2; ++mi)
#pragma unroll
          for (int ni = 0; ni < 4; ++ni)
            acc[mi][ni] = __builtin_amdgcn_mfma_f32_16x16x32_bf16(bfr[ni], af[mi], acc[mi][ni], 0, 0, 0);
      } else {
#pragma unroll
        for (int mi = 0; mi < 2; ++mi)
#pragma unroll
          for (int ni = 0; ni < 4; ++ni)
            acc[mi][ni] = __builtin_amdgcn_mfma_f32_16x16x32_bf16(af[mi], bfr[ni], acc[mi][ni], 0, 0, 0);
      }
    }
    cur ^= 1;
  }

  if (!vblk) {
    // Swapped: T1[m0+wm*32+mi*16+l16][bn*256+wn*64+ni*16+lh*4+r]
    const long rown = (long)(m0 + wm * 32 + l16);
    const int coln = bn * 256 + wn * 64 + lh * 4;
#pragma unroll
    for (int mi = 0; mi < 2; ++mi)
#pragma unroll
      for (int ni = 0; ni < 4; ++ni) {
        u16x4 o;
#pragma unroll
        for (int r = 0; r < 4; ++r) o[r] = f2bf(acc[mi][ni][r]);
        *reinterpret_cast<u16x4*>(&T1[(rown + mi * 16) * 1024 + coln + ni * 16]) = o;
      }
  } else {
    // V (normal order): D row = M-dim(t). Vt[b][e][t], vector along t.
    const int b = m0 >> 11;
    const int t0 = (m0 & 2047) + wm * 32 + lh * 4;
    const int e0 = (bn - 4) * 256 + wn * 64 + l16;
#pragma unroll
    for (int mi = 0; mi < 2; ++mi)
#pragma unroll
      for (int ni = 0; ni < 4; ++ni) {
        u16x4 o;
#pragma unroll
        for (int r = 0; r < 4; ++r) o[r] = f2bf(acc[mi][ni][r]);
        *reinterpret_cast<u16x4*>(
            &Vt[(long)b * 2097152 + (long)(e0 + ni * 16) * 2048 + t0 + mi * 16]) = o;
      }
  }
}

// ---------------- S = exp(T1 X^T): 64x128 tiles, BK=64, 3/CU (r13, unchanged) -----
__global__ __launch_bounds__(256, 3) void gemm_s(const u16* __restrict__ T1,
                                                 const u16* __restrict__ Xb,
                                                 u16* __restrict__ Sg,
                                                 float* __restrict__ Sums) {
  const int id = blockIdx.x;            // 0..1087
  const int x = id & 7;                 // XCD (round-robin assumption)
  const int q = id >> 3;                // 0..135
  const int bz = q / 34;
  int u = q - bz * 34;
  int qr, kc;
  const int n1 = 32 - 2 * x;            // tiles with kc = x  (qr = 2x..31)
  if (u < n1) { kc = x;      qr = 2 * x + u; }
  else        { kc = 15 - x; qr = 30 - 2 * x + (u - n1); }
  const int m0 = qr * 64, n0 = kc * 128;
  const int K = 1024;

  const u16* A = T1 + (long)bz * 2097152;
  const u16* B = Xb + (long)bz * 2097152;

  __shared__ u16 ldsA[2][4096];    // 64 x 64
  __shared__ u16 ldsB[2][8192];    // 128 x 64

  const int tid = threadIdx.x;          // 0..255
  const int lane = tid & 63;
  const int wn = tid >> 6;              // wave 0..3 owns cols wn*32..wn*32+31
  const int l16 = lane & 15, lh = lane >> 4;
  const int strow = tid >> 3;                       // 0..31
  const int scol = ((tid & 7) ^ (strow & 7)) * 8;   // pre-swizzled source col
  const int rsw = l16 & 7;                          // read-side swizzle key

  f32x4 acc[4][2];
#pragma unroll
  for (int mi = 0; mi < 4; ++mi)
#pragma unroll
    for (int ni = 0; ni < 2; ++ni) acc[mi][ni] = (f32x4)(0.0f);

  auto stage = [&](int d, int k0) {
#pragma unroll
    for (int l = 0; l < 2; ++l)
      gload_lds16(A + (long)(m0 + l * 32 + strow) * K + k0 + scol,
                  &ldsA[d][l * 2048 + tid * 8]);
#pragma unroll
    for (int l = 0; l < 4; ++l)
      gload_lds16(B + (long)(n0 + l * 32 + strow) * K + k0 + scol,
                  &ldsB[d][l * 2048 + tid * 8]);
  };

  stage(0, 0);
  int cur = 0;
  for (int k0 = 0; k0 < K; k0 += 64) {
    __syncthreads();
    if (k0 + 64 < K) stage(cur ^ 1, k0 + 64);
#pragma unroll
    for (int kk = 0; kk < 2; ++kk) {
      bf16x8 af[4], bfr[2];
#pragma unroll
      for (int mi = 0; mi < 4; ++mi)
        af[mi] = *reinterpret_cast<const bf16x8*>(
            &ldsA[cur][(mi * 16 + l16) * 64 + (((kk * 4 + lh) ^ rsw)) * 8]);
#pragma unroll
      for (int ni = 0; ni < 2; ++ni)
        bfr[ni] = *reinterpret_cast<const bf16x8*>(
            &ldsB[cur][(wn * 32 + ni * 16 + l16) * 64 + (((kk * 4 + lh) ^ rsw)) * 8]);
#pragma unroll
      for (int mi = 0; mi < 4; ++mi)
#pragma unroll
        for (int ni = 0; ni < 2; ++ni)
          acc[mi][ni] = __builtin_amdgcn_mfma_f32_16x16x32_bf16(bfr[ni], af[mi], acc[mi][ni], 0, 0, 0);
    }
    cur ^= 1;
  }

  // P = exp(S), zero above diagonal; row sums from bf16-rounded values.
  u16* C = Sg + (long)bz * 4194304;
  float* sums = Sums + (long)bz * 2048;
  const int coln = n0 + wn * 32 + lh * 4;
#pragma unroll
  for (int mi = 0; mi < 4; ++mi) {
    const int gr = m0 + mi * 16 + l16;
    float rs = 0.0f;
#pragma unroll
    for (int ni = 0; ni < 2; ++ni) {
      u16x4 o;
#pragma unroll
      for (int r = 0; r < 4; ++r) {
        const int gc = coln + ni * 16 + r;
        const float e = (gc <= gr) ? __expf(acc[mi][ni][r]) : 0.0f;
        const u16 ub = f2bf(e);
        o[r] = ub;
        rs += bf2f(ub);
      }
      *reinterpret_cast<u16x4*>(&C[(long)gr * 2048 + coln + ni * 16]) = o;
    }
    rs += __shfl_xor(rs, 16);
    rs += __shfl_xor(rs, 32);
    if (lh == 0) atomicAdd(&sums[gr], rs);
  }
}

// ---------------- PV GEMM: 128x128, 8 waves, balanced pairing (r13, unchanged) ----
__global__ __launch_bounds__(512, 2) void gemm_pv(const u16* __restrict__ Ag,
                                                  const u16* __restrict__ Bg,
                                                  float* __restrict__ Cg,
                                                  const float* __restrict__ Sums) {
  const int id = blockIdx.x;            // 0..511
  const int x = id & 7;                 // XCD; also bn
  const int q = id >> 3;                // 0..63
  const int f = (q ^ (q >> 5)) & 1;
  const int i5 = ((q >> 1) & 15) | (((q >> 5) & 1) << 4);
  const int bmb = i5 & 7;
  const int bz = (i5 >> 3) & 3;
  const int bm = f ? (15 - bmb) : bmb;
  const int bn = x;
  const int K = 2048;

  const u16* A = Ag + (long)bz * 4194304;
  const u16* B = Bg + (long)bz * 2097152;
  const int m0 = bm * 128, n0 = bn * 128;
  const int kEnd = m0 + 128;

  __shared__ u16 ldsA[2][8192];
  __shared__ u16 ldsB[2][8192];

  const int tid = threadIdx.x;          // 0..511
  const int lane = tid & 63;
  const int wid = tid >> 6;             // 0..7
  const int wm = wid >> 2, wn = wid & 3;
  const int l16 = lane & 15, lh = lane >> 4;
  const int strow = tid >> 3;                       // 0..63
  const int scol = ((tid & 7) ^ (strow & 7)) * 8;   // pre-swizzled source column
  const int rsw = l16 & 7;                          // read-side swizzle key

  f32x4 acc[4][2];
#pragma unroll
  for (int mi = 0; mi < 4; ++mi)
#pragma unroll
    for (int ni = 0; ni < 2; ++ni) acc[mi][ni] = (f32x4)(0.0f);

  auto stage = [&](int d, int k0) {
#pragma unroll
    for (int l = 0; l < 2; ++l) {
      const int row = l * 64 + strow;   // 0..127
      gload_lds16(A + (long)(m0 + row) * K + k0 + scol, &ldsA[d][l * 4096 + tid * 8]);
      gload_lds16(B + (long)(n0 + row) * K + k0 + scol, &ldsB[d][l * 4096 + tid * 8]);
    }
  };

  stage(0, 0);
  int cur = 0;
  for (int k0 = 0; k0 < kEnd; k0 += 64) {
    __syncthreads();
    if (k0 + 64 < kEnd) stage(cur ^ 1, k0 + 64);
#pragma unroll
    for (int kk = 0; kk < 2; ++kk) {
      bf16x8 af[4], bfr[2];
#pragma unroll
      for (int mi = 0; mi < 4; ++mi)
        af[mi] = *reinterpret_cast<const bf16x8*>(
            &ldsA[cur][(wm * 64 + mi * 16 + l16) * 64 + (((kk * 4 + lh) ^ rsw)) * 8]);
#pragma unroll
      for (int ni = 0; ni < 2; ++ni)
        bfr[ni] = *reinterpret_cast<const bf16x8*>(
            &ldsB[cur][(wn * 32 + ni * 16 + l16) * 64 + (((kk * 4 + lh) ^ rsw)) * 8]);
#pragma unroll
      for (int mi = 0; mi < 4; ++mi)
#pragma unroll
        for (int ni = 0; ni < 2; ++ni)
          acc[mi][ni] = __builtin_amdgcn_mfma_f32_16x16x32_bf16(bfr[ni], af[mi], acc[mi][ni], 0, 0, 0);
    }
    cur ^= 1;
  }

  // O = acc / rowsum
  float* C = Cg + (long)bz * 2097152;
  const float* sums = Sums + (long)bz * 2048;
  const long rown = (long)(m0 + wm * 64 + l16);
  const int coln = n0 + wn * 32 + lh * 4;
#pragma unroll
  for (int mi = 0; mi < 4; ++mi) {
    const float inv = 1.0f / sums[(int)rown + mi * 16];
#pragma unroll
    for (int ni = 0; ni < 2; ++ni) {
      f32x4 v = acc[mi][ni] * inv;
      *reinterpret_cast<f32x4*>(&C[(rown + mi * 16) * 1024 + coln + ni * 16]) = v;
    }
  }
}

extern "C" void kernel_launch(void* const* d_in, const int* in_sizes, int n_in,
                              void* d_out, int out_size, void* d_ws, size_t ws_size,
                              hipStream_t stream) {
  const float* X  = (const float*)d_in[0];
  const float* Wq = (const float*)d_in[1];
  const float* Wk = (const float*)d_in[2];
  const float* Wv = (const float*)d_in[3];

  // workspace layout (u16 elements)
  u16* Xb  = (u16*)d_ws;                // 8192*1024
  u16* Wqr = Xb + 8388608;              // 1M, row-major Wq*(1/32)
  u16* Wkr = Wqr + 1048576;             // 1M, row-major Wk
  u16* WG  = Wkr + 1048576;             // [Gt; Wvt] (2M) — contiguous B for T1V
  u16* T1  = WG + 2097152;              // 8192*1024
  u16* Vt  = T1 + 8388608;              // [b][1024][2048]
  u16* S   = Vt + 8388608;              // [b][2048][2048] -> holds P = exp(scores)
  float* sums = (float*)(S + 16777216); // [b][2048] row sums (32 KB)

  hipMemsetAsync(sums, 0, 4 * 2048 * sizeof(float), stream);

  // cast X, Wq (scaled), Wk row-major; transpose Wv (one dispatch)
  prep_kernel<<<5376, 256, 0, stream>>>(X, Wq, Wk, Wv, Xb, Wqr, Wkr, WG + 1048576);

  // Gt = NT(Wkr, Wqr): Gt[d'][d] = M[d,d'] — 2.1 GF, proven dbuf kernel (~5us)
  gemm_g<<<64, 256, 0, stream>>>(Wkr, Wqr, WG);

  // [T1 | V] = NT(Xb, [Gt; Wvt]) — 64x256 tile, 8 waves, 1024 blocks = 2 rounds
  gemm_t1v<<<1024, 512, 0, stream>>>(Xb, WG, T1, Vt);

  // P = exp(T1 X^T) per batch (causal zeros; row sums via atomics)
  gemm_s<<<1088, 256, 0, stream>>>(T1, Xb, S, sums);

  // O = P V / rowsum
  gemm_pv<<<512, 512, 0, stream>>>(S, Vt, (float*)d_out, sums);
}

// Round 18
// 131.834 us; speedup vs baseline: 1.3436x; 1.0226x over previous
//
#include <hip/hip_runtime.h>
#include <hip/hip_bf16.h>

typedef unsigned short u16;
typedef __bf16 bf16x8 __attribute__((ext_vector_type(8)));
typedef float f32x4 __attribute__((ext_vector_type(4)));
typedef unsigned short u16x8 __attribute__((ext_vector_type(8)));
typedef unsigned short u16x4 __attribute__((ext_vector_type(4)));

__device__ __forceinline__ float bf2f(u16 u) {
  unsigned int x = ((unsigned int)u) << 16;
  return __builtin_bit_cast(float, x);
}
__device__ __forceinline__ u16 f2bf(float f) {
  unsigned int x = __builtin_bit_cast(unsigned int, f);
  x = x + 0x7FFFu + ((x >> 16) & 1u);
  return (u16)(x >> 16);
}

// async global->LDS, 16B per lane; LDS dest is wave-uniform base + lane*16.
__device__ __forceinline__ void gload_lds16(const u16* g, u16* l) {
  __builtin_amdgcn_global_load_lds(
      (const __attribute__((address_space(1))) unsigned int*)(unsigned long long)(uintptr_t)g,
      (__attribute__((address_space(3))) unsigned int*)(unsigned int)(uintptr_t)l,
      16, 0, 0);
}

// ---------------- prep: cast X, Wq*(1/32), Wk; transpose Wv (r15/r17) ----------
__global__ __launch_bounds__(256) void prep_kernel(const float* __restrict__ X,
                                                   const float* __restrict__ Wq,
                                                   const float* __restrict__ Wk,
                                                   const float* __restrict__ Wv,
                                                   u16* __restrict__ Xb,
                                                   u16* __restrict__ Wqr,
                                                   u16* __restrict__ Wkr,
                                                   u16* __restrict__ Wvt) {
  const int id = blockIdx.x;
  const int tid = threadIdx.x;
  if (id < 5120) {
    const float* src;
    u16* dst;
    float scale = 1.0f;
    long i;
    if (id < 4096) {
      src = X; dst = Xb; i = ((long)id * 256 + tid) * 8;
    } else if (id < 4608) {
      src = Wq; dst = Wqr; scale = 1.0f / 32.0f;   // fold 1/sqrt(1024)
      i = ((long)(id - 4096) * 256 + tid) * 8;
    } else {
      src = Wk; dst = Wkr;
      i = ((long)(id - 4608) * 256 + tid) * 8;
    }
    float4 a = *reinterpret_cast<const float4*>(src + i);
    float4 b = *reinterpret_cast<const float4*>(src + i + 4);
    u16x8 o;
    o[0] = f2bf(a.x * scale); o[1] = f2bf(a.y * scale);
    o[2] = f2bf(a.z * scale); o[3] = f2bf(a.w * scale);
    o[4] = f2bf(b.x * scale); o[5] = f2bf(b.y * scale);
    o[6] = f2bf(b.z * scale); o[7] = f2bf(b.w * scale);
    *reinterpret_cast<u16x8*>(dst + i) = o;
    return;
  }
  // Wv transpose: Wvt[c*1024 + r] = Wv[r][c]
  __shared__ u16 t[64][72];
  const int id2 = id - 5120;          // 0..255
  const int c0 = (id2 & 15) * 64;
  const int r0 = (id2 >> 4) * 64;
#pragma unroll
  for (int i = 0; i < 4; ++i) {
    int slot = tid + 256 * i;
    int lr = slot >> 4;
    int lc4 = slot & 15;
    float4 v = *reinterpret_cast<const float4*>(Wv + (long)(r0 + lr) * 1024 + c0 + lc4 * 4);
    t[lr][lc4 * 4 + 0] = f2bf(v.x);
    t[lr][lc4 * 4 + 1] = f2bf(v.y);
    t[lr][lc4 * 4 + 2] = f2bf(v.z);
    t[lr][lc4 * 4 + 3] = f2bf(v.w);
  }
  __syncthreads();
#pragma unroll
  for (int i = 0; i < 2; ++i) {
    int slot = tid + 256 * i;
    int orow = slot >> 3;
    int oc = slot & 7;
    u16x8 o;
#pragma unroll
    for (int j = 0; j < 8; ++j) o[j] = t[oc * 8 + j][orow];
    *reinterpret_cast<u16x8*>(Wvt + (long)(c0 + orow) * 1024 + r0 + oc * 8) = o;
  }
}

// ---------------- G: Gt = NT(Wkr, Wqr), 128x128, 4 waves (r17, unchanged) ----------
__global__ __launch_bounds__(256, 2) void gemm_g(const u16* __restrict__ A,
                                                 const u16* __restrict__ B,
                                                 u16* __restrict__ Gt) {
  const int bm = blockIdx.x >> 3;       // 0..7
  const int bn = blockIdx.x & 7;
  const int m0 = bm * 128, n0 = bn * 128;
  const int K = 1024;

  __shared__ u16 ldsA[2][8192];
  __shared__ u16 ldsB[2][8192];

  const int tid = threadIdx.x;
  const int lane = tid & 63;
  const int wid = tid >> 6;
  const int wm = wid >> 1, wn = wid & 1;
  const int l16 = lane & 15, lh = lane >> 4;
  const int srow = lane >> 3;
  const int scol = ((lane & 7) ^ srow) * 8;  // pre-swizzled source column
  const int rsw = l16 & 7;                   // read-side swizzle key

  f32x4 acc[4][4];
#pragma unroll
  for (int mi = 0; mi < 4; ++mi)
#pragma unroll
    for (int ni = 0; ni < 4; ++ni) acc[mi][ni] = (f32x4)(0.0f);

  auto stage = [&](int d, int k0) {
#pragma unroll
    for (int s = 0; s < 4; ++s) {
      const int seg = wid * 4 + s;           // 0..15 (1KB segments)
      const int row = seg * 8 + srow;        // 0..127
      gload_lds16(A + (long)(m0 + row) * K + k0 + scol, &ldsA[d][seg * 512]);
      gload_lds16(B + (long)(n0 + row) * K + k0 + scol, &ldsB[d][seg * 512]);
    }
  };

  stage(0, 0);
  int cur = 0;
  for (int k0 = 0; k0 < K; k0 += 64) {
    __syncthreads();
    if (k0 + 64 < K) stage(cur ^ 1, k0 + 64);
#pragma unroll
    for (int kk = 0; kk < 2; ++kk) {
      bf16x8 af[4], bfr[4];
#pragma unroll
      for (int mi = 0; mi < 4; ++mi)
        af[mi] = *reinterpret_cast<const bf16x8*>(
            &ldsA[cur][(wm * 64 + mi * 16 + l16) * 64 + (((kk * 4 + lh) ^ rsw)) * 8]);
#pragma unroll
      for (int ni = 0; ni < 4; ++ni)
        bfr[ni] = *reinterpret_cast<const bf16x8*>(
            &ldsB[cur][(wn * 64 + ni * 16 + l16) * 64 + (((kk * 4 + lh) ^ rsw)) * 8]);
#pragma unroll
      for (int mi = 0; mi < 4; ++mi)
#pragma unroll
        for (int ni = 0; ni < 4; ++ni)
          acc[mi][ni] = __builtin_amdgcn_mfma_f32_16x16x32_bf16(bfr[ni], af[mi], acc[mi][ni], 0, 0, 0);
    }
    cur ^= 1;
  }

  // Swapped: Gt[m0+wm*64+mi*16+l16][n0+wn*64+ni*16+lh*4+r]
  const long rown = (long)(m0 + wm * 64 + l16);
  const int coln = n0 + wn * 64 + lh * 4;
#pragma unroll
  for (int mi = 0; mi < 4; ++mi)
#pragma unroll
    for (int ni = 0; ni < 4; ++ni) {
      u16x4 o;
#pragma unroll
      for (int r = 0; r < 4; ++r) o[r] = f2bf(acc[mi][ni][r]);
      *reinterpret_cast<u16x4*>(&Gt[(rown + mi * 16) * 1024 + coln + ni * 16]) = o;
    }
}

// ---------------- [T1|V] = NT(Xb, [Gt;Wvt]): 128x128, 8 waves (r18) ----------
// r17 post-mortem: 64x256 = 661 TF (worst geometry: 40KB staged / 2.1 MFLOP
// per K-step). r10's 8-wave 128^2 measured 777 TF (32KB / 2.1 MFLOP). Use it.
// Grid 64x16 = 1024 blocks = exactly 2.0 rounds at 2/CU. Waves 64x32
// (acc[4][2]). bn<8 -> T1 (swapped epilogue); bn>=8 -> V (normal order,
// transposed store to Vt[b][e][t]).
__global__ __launch_bounds__(512, 2) void gemm_t1v(const u16* __restrict__ Xb,
                                                   const u16* __restrict__ WG,
                                                   u16* __restrict__ T1,
                                                   u16* __restrict__ Vt) {
  const int id = blockIdx.x;            // 0..1023
  const int xcd = id & 7, j = id >> 3;  // j: 0..127
  const int bn = (xcd & 1) * 8 + (j & 7);        // 0..15
  const int bm = ((xcd >> 1) << 4) + (j >> 3);   // 0..63
  const int m0 = bm * 128, n0 = bn * 128;
  const int K = 1024;

  __shared__ u16 ldsA[2][8192];
  __shared__ u16 ldsB[2][8192];

  const int tid = threadIdx.x;          // 0..511
  const int lane = tid & 63;
  const int wid = tid >> 6;             // 0..7
  const int wm = wid >> 2, wn = wid & 3;
  const int l16 = lane & 15, lh = lane >> 4;
  const int strow = tid >> 3;                       // 0..63
  const int scol = ((tid & 7) ^ (strow & 7)) * 8;   // pre-swizzled source col
  const int rsw = l16 & 7;                          // read-side swizzle key

  const bool vblk = (bn >= 8);

  f32x4 acc[4][2];
#pragma unroll
  for (int mi = 0; mi < 4; ++mi)
#pragma unroll
    for (int ni = 0; ni < 2; ++ni) acc[mi][ni] = (f32x4)(0.0f);

  auto stage = [&](int d, int k0) {
#pragma unroll
    for (int l = 0; l < 2; ++l) {
      const int row = l * 64 + strow;   // 0..127
      gload_lds16(Xb + (long)(m0 + row) * K + k0 + scol, &ldsA[d][l * 4096 + tid * 8]);
      gload_lds16(WG + (long)(n0 + row) * K + k0 + scol, &ldsB[d][l * 4096 + tid * 8]);
    }
  };

  stage(0, 0);
  int cur = 0;
  for (int k0 = 0; k0 < K; k0 += 64) {
    __syncthreads();                          // buf[cur] ready; old readers done
    if (k0 + 64 < K) stage(cur ^ 1, k0 + 64); // lands during compute below
#pragma unroll
    for (int kk = 0; kk < 2; ++kk) {
      bf16x8 af[4], bfr[2];
#pragma unroll
      for (int mi = 0; mi < 4; ++mi)
        af[mi] = *reinterpret_cast<const bf16x8*>(
            &ldsA[cur][(wm * 64 + mi * 16 + l16) * 64 + (((kk * 4 + lh) ^ rsw)) * 8]);
#pragma unroll
      for (int ni = 0; ni < 2; ++ni)
        bfr[ni] = *reinterpret_cast<const bf16x8*>(
            &ldsB[cur][(wn * 32 + ni * 16 + l16) * 64 + (((kk * 4 + lh) ^ rsw)) * 8]);
      if (!vblk) {
#pragma unroll
        for (int mi = 0; mi < 4; ++mi)
#pragma unroll
          for (int ni = 0; ni < 2; ++ni)
            acc[mi][ni] = __builtin_amdgcn_mfma_f32_16x16x32_bf16(bfr[ni], af[mi], acc[mi][ni], 0, 0, 0);
      } else {
#pragma unroll
        for (int mi = 0; mi < 4; ++mi)
#pragma unroll
          for (int ni = 0; ni < 2; ++ni)
            acc[mi][ni] = __builtin_amdgcn_mfma_f32_16x16x32_bf16(af[mi], bfr[ni], acc[mi][ni], 0, 0, 0);
      }
    }
    cur ^= 1;
  }

  if (!vblk) {
    // Swapped: T1[m0+wm*64+mi*16+l16][bn*128+wn*32+ni*16+lh*4+r]
    const long rown = (long)(m0 + wm * 64 + l16);
    const int coln = bn * 128 + wn * 32 + lh * 4;
#pragma unroll
    for (int mi = 0; mi < 4; ++mi)
#pragma unroll
      for (int ni = 0; ni < 2; ++ni) {
        u16x4 o;
#pragma unroll
        for (int r = 0; r < 4; ++r) o[r] = f2bf(acc[mi][ni][r]);
        *reinterpret_cast<u16x4*>(&T1[(rown + mi * 16) * 1024 + coln + ni * 16]) = o;
      }
  } else {
    // V (normal order): D row = M-dim(t). Vt[b][e][t], vector along t.
    const int b = m0 >> 11;
    const int t0 = (m0 & 2047) + wm * 64 + lh * 4;
    const int e0 = (bn - 8) * 128 + wn * 32 + l16;
#pragma unroll
    for (int mi = 0; mi < 4; ++mi)
#pragma unroll
      for (int ni = 0; ni < 2; ++ni) {
        u16x4 o;
#pragma unroll
        for (int r = 0; r < 4; ++r) o[r] = f2bf(acc[mi][ni][r]);
        *reinterpret_cast<u16x4*>(
            &Vt[(long)b * 2097152 + (long)(e0 + ni * 16) * 2048 + t0 + mi * 16]) = o;
      }
  }
}

// ---------------- S = exp(T1 X^T): 64x128 tiles, BK=64, 4/CU (r18) -----
// r18: LDS is only 24KB -> raise occupancy 3->4 blocks/CU (VGPR cap 128,
// est ~100 used, no spill expected). 1088 blocks on 1024 slots = 1.06 rounds
// (was 1.42 at 3/CU). kc->XCD affinity unchanged.
__global__ __launch_bounds__(256, 4) void gemm_s(const u16* __restrict__ T1,
                                                 const u16* __restrict__ Xb,
                                                 u16* __restrict__ Sg,
                                                 float* __restrict__ Sums) {
  const int id = blockIdx.x;            // 0..1087
  const int x = id & 7;                 // XCD (round-robin assumption)
  const int q = id >> 3;                // 0..135
  const int bz = q / 34;
  int u = q - bz * 34;
  int qr, kc;
  const int n1 = 32 - 2 * x;            // tiles with kc = x  (qr = 2x..31)
  if (u < n1) { kc = x;      qr = 2 * x + u; }
  else        { kc = 15 - x; qr = 30 - 2 * x + (u - n1); }
  const int m0 = qr * 64, n0 = kc * 128;
  const int K = 1024;

  const u16* A = T1 + (long)bz * 2097152;
  const u16* B = Xb + (long)bz * 2097152;

  __shared__ u16 ldsA[2][4096];    // 64 x 64
  __shared__ u16 ldsB[2][8192];    // 128 x 64

  const int tid = threadIdx.x;          // 0..255
  const int lane = tid & 63;
  const int wn = tid >> 6;              // wave 0..3 owns cols wn*32..wn*32+31
  const int l16 = lane & 15, lh = lane >> 4;
  const int strow = tid >> 3;                       // 0..31
  const int scol = ((tid & 7) ^ (strow & 7)) * 8;   // pre-swizzled source col
  const int rsw = l16 & 7;                          // read-side swizzle key

  f32x4 acc[4][2];
#pragma unroll
  for (int mi = 0; mi < 4; ++mi)
#pragma unroll
    for (int ni = 0; ni < 2; ++ni) acc[mi][ni] = (f32x4)(0.0f);

  auto stage = [&](int d, int k0) {
#pragma unroll
    for (int l = 0; l < 2; ++l)
      gload_lds16(A + (long)(m0 + l * 32 + strow) * K + k0 + scol,
                  &ldsA[d][l * 2048 + tid * 8]);
#pragma unroll
    for (int l = 0; l < 4; ++l)
      gload_lds16(B + (long)(n0 + l * 32 + strow) * K + k0 + scol,
                  &ldsB[d][l * 2048 + tid * 8]);
  };

  stage(0, 0);
  int cur = 0;
  for (int k0 = 0; k0 < K; k0 += 64) {
    __syncthreads();
    if (k0 + 64 < K) stage(cur ^ 1, k0 + 64);
#pragma unroll
    for (int kk = 0; kk < 2; ++kk) {
      bf16x8 af[4], bfr[2];
#pragma unroll
      for (int mi = 0; mi < 4; ++mi)
        af[mi] = *reinterpret_cast<const bf16x8*>(
            &ldsA[cur][(mi * 16 + l16) * 64 + (((kk * 4 + lh) ^ rsw)) * 8]);
#pragma unroll
      for (int ni = 0; ni < 2; ++ni)
        bfr[ni] = *reinterpret_cast<const bf16x8*>(
            &ldsB[cur][(wn * 32 + ni * 16 + l16) * 64 + (((kk * 4 + lh) ^ rsw)) * 8]);
#pragma unroll
      for (int mi = 0; mi < 4; ++mi)
#pragma unroll
        for (int ni = 0; ni < 2; ++ni)
          acc[mi][ni] = __builtin_amdgcn_mfma_f32_16x16x32_bf16(bfr[ni], af[mi], acc[mi][ni], 0, 0, 0);
    }
    cur ^= 1;
  }

  // P = exp(S), zero above diagonal; row sums from bf16-rounded values.
  u16* C = Sg + (long)bz * 4194304;
  float* sums = Sums + (long)bz * 2048;
  const int coln = n0 + wn * 32 + lh * 4;
#pragma unroll
  for (int mi = 0; mi < 4; ++mi) {
    const int gr = m0 + mi * 16 + l16;
    float rs = 0.0f;
#pragma unroll
    for (int ni = 0; ni < 2; ++ni) {
      u16x4 o;
#pragma unroll
      for (int r = 0; r < 4; ++r) {
        const int gc = coln + ni * 16 + r;
        const float e = (gc <= gr) ? __expf(acc[mi][ni][r]) : 0.0f;
        const u16 ub = f2bf(e);
        o[r] = ub;
        rs += bf2f(ub);
      }
      *reinterpret_cast<u16x4*>(&C[(long)gr * 2048 + coln + ni * 16]) = o;
    }
    rs += __shfl_xor(rs, 16);
    rs += __shfl_xor(rs, 32);
    if (lh == 0) atomicAdd(&sums[gr], rs);
  }
}

// ---------------- PV GEMM: 128x128, 8 waves, balanced pairing (r13, unchanged) ----
__global__ __launch_bounds__(512, 2) void gemm_pv(const u16* __restrict__ Ag,
                                                  const u16* __restrict__ Bg,
                                                  float* __restrict__ Cg,
                                                  const float* __restrict__ Sums) {
  const int id = blockIdx.x;            // 0..511
  const int x = id & 7;                 // XCD; also bn
  const int q = id >> 3;                // 0..63
  const int f = (q ^ (q >> 5)) & 1;
  const int i5 = ((q >> 1) & 15) | (((q >> 5) & 1) << 4);
  const int bmb = i5 & 7;
  const int bz = (i5 >> 3) & 3;
  const int bm = f ? (15 - bmb) : bmb;
  const int bn = x;
  const int K = 2048;

  const u16* A = Ag + (long)bz * 4194304;
  const u16* B = Bg + (long)bz * 2097152;
  const int m0 = bm * 128, n0 = bn * 128;
  const int kEnd = m0 + 128;

  __shared__ u16 ldsA[2][8192];
  __shared__ u16 ldsB[2][8192];

  const int tid = threadIdx.x;          // 0..511
  const int lane = tid & 63;
  const int wid = tid >> 6;             // 0..7
  const int wm = wid >> 2, wn = wid & 3;
  const int l16 = lane & 15, lh = lane >> 4;
  const int strow = tid >> 3;                       // 0..63
  const int scol = ((tid & 7) ^ (strow & 7)) * 8;   // pre-swizzled source column
  const int rsw = l16 & 7;                          // read-side swizzle key

  f32x4 acc[4][2];
#pragma unroll
  for (int mi = 0; mi < 4; ++mi)
#pragma unroll
    for (int ni = 0; ni < 2; ++ni) acc[mi][ni] = (f32x4)(0.0f);

  auto stage = [&](int d, int k0) {
#pragma unroll
    for (int l = 0; l < 2; ++l) {
      const int row = l * 64 + strow;   // 0..127
      gload_lds16(A + (long)(m0 + row) * K + k0 + scol, &ldsA[d][l * 4096 + tid * 8]);
      gload_lds16(B + (long)(n0 + row) * K + k0 + scol, &ldsB[d][l * 4096 + tid * 8]);
    }
  };

  stage(0, 0);
  int cur = 0;
  for (int k0 = 0; k0 < kEnd; k0 += 64) {
    __syncthreads();
    if (k0 + 64 < kEnd) stage(cur ^ 1, k0 + 64);
#pragma unroll
    for (int kk = 0; kk < 2; ++kk) {
      bf16x8 af[4], bfr[2];
#pragma unroll
      for (int mi = 0; mi < 4; ++mi)
        af[mi] = *reinterpret_cast<const bf16x8*>(
            &ldsA[cur][(wm * 64 + mi * 16 + l16) * 64 + (((kk * 4 + lh) ^ rsw)) * 8]);
#pragma unroll
      for (int ni = 0; ni < 2; ++ni)
        bfr[ni] = *reinterpret_cast<const bf16x8*>(
            &ldsB[cur][(wn * 32 + ni * 16 + l16) * 64 + (((kk * 4 + lh) ^ rsw)) * 8]);
#pragma unroll
      for (int mi = 0; mi < 4; ++mi)
#pragma unroll
        for (int ni = 0; ni < 2; ++ni)
          acc[mi][ni] = __builtin_amdgcn_mfma_f32_16x16x32_bf16(bfr[ni], af[mi], acc[mi][ni], 0, 0, 0);
    }
    cur ^= 1;
  }

  // O = acc / rowsum
  float* C = Cg + (long)bz * 2097152;
  const float* sums = Sums + (long)bz * 2048;
  const long rown = (long)(m0 + wm * 64 + l16);
  const int coln = n0 + wn * 32 + lh * 4;
#pragma unroll
  for (int mi = 0; mi < 4; ++mi) {
    const float inv = 1.0f / sums[(int)rown + mi * 16];
#pragma unroll
    for (int ni = 0; ni < 2; ++ni) {
      f32x4 v = acc[mi][ni] * inv;
      *reinterpret_cast<f32x4*>(&C[(rown + mi * 16) * 1024 + coln + ni * 16]) = v;
    }
  }
}

extern "C" void kernel_launch(void* const* d_in, const int* in_sizes, int n_in,
                              void* d_out, int out_size, void* d_ws, size_t ws_size,
                              hipStream_t stream) {
  const float* X  = (const float*)d_in[0];
  const float* Wq = (const float*)d_in[1];
  const float* Wk = (const float*)d_in[2];
  const float* Wv = (const float*)d_in[3];

  // workspace layout (u16 elements)
  u16* Xb  = (u16*)d_ws;                // 8192*1024
  u16* Wqr = Xb + 8388608;              // 1M, row-major Wq*(1/32)
  u16* Wkr = Wqr + 1048576;             // 1M, row-major Wk
  u16* WG  = Wkr + 1048576;             // [Gt; Wvt] (2M) — contiguous B for T1V
  u16* T1  = WG + 2097152;              // 8192*1024
  u16* Vt  = T1 + 8388608;              // [b][1024][2048]
  u16* S   = Vt + 8388608;              // [b][2048][2048] -> holds P = exp(scores)
  float* sums = (float*)(S + 16777216); // [b][2048] row sums (32 KB)

  hipMemsetAsync(sums, 0, 4 * 2048 * sizeof(float), stream);

  // cast X, Wq (scaled), Wk row-major; transpose Wv (one dispatch)
  prep_kernel<<<5376, 256, 0, stream>>>(X, Wq, Wk, Wv, Xb, Wqr, Wkr, WG + 1048576);

  // Gt = NT(Wkr, Wqr): Gt[d'][d] = M[d,d'] — 2.1 GF, proven dbuf kernel (~5us)
  gemm_g<<<64, 256, 0, stream>>>(Wkr, Wqr, WG);

  // [T1 | V] = NT(Xb, [Gt; Wvt]) — 128x128, 8 waves, 1024 blocks = 2 rounds
  gemm_t1v<<<1024, 512, 0, stream>>>(Xb, WG, T1, Vt);

  // P = exp(T1 X^T) per batch (causal zeros; row sums via atomics), 4/CU
  gemm_s<<<1088, 256, 0, stream>>>(T1, Xb, S, sums);

  // O = P V / rowsum
  gemm_pv<<<512, 512, 0, stream>>>(S, Vt, (float*)d_out, sums);
}

// Round 19
// 126.884 us; speedup vs baseline: 1.3960x; 1.0390x over previous
//
#include <hip/hip_runtime.h>
#include <hip/hip_bf16.h>

typedef unsigned short u16;
typedef __bf16 bf16x8 __attribute__((ext_vector_type(8)));
typedef float f32x4 __attribute__((ext_vector_type(4)));
typedef unsigned short u16x8 __attribute__((ext_vector_type(8)));
typedef unsigned short u16x4 __attribute__((ext_vector_type(4)));

__device__ __forceinline__ float bf2f(u16 u) {
  unsigned int x = ((unsigned int)u) << 16;
  return __builtin_bit_cast(float, x);
}
__device__ __forceinline__ u16 f2bf(float f) {
  unsigned int x = __builtin_bit_cast(unsigned int, f);
  x = x + 0x7FFFu + ((x >> 16) & 1u);
  return (u16)(x >> 16);
}

// async global->LDS, 16B per lane; LDS dest is wave-uniform base + lane*16.
__device__ __forceinline__ void gload_lds16(const u16* g, u16* l) {
  __builtin_amdgcn_global_load_lds(
      (const __attribute__((address_space(1))) unsigned int*)(unsigned long long)(uintptr_t)g,
      (__attribute__((address_space(3))) unsigned int*)(unsigned int)(uintptr_t)l,
      16, 0, 0);
}

// ---------------- prep: cast X, Wq*(1/32), Wk; transpose Wv; zero sums ----------
// r19: sums zeroing folded in (block 5376) -> drops the hipMemsetAsync
// dispatch and its inter-dispatch gap.
__global__ __launch_bounds__(256) void prep_kernel(const float* __restrict__ X,
                                                   const float* __restrict__ Wq,
                                                   const float* __restrict__ Wk,
                                                   const float* __restrict__ Wv,
                                                   u16* __restrict__ Xb,
                                                   u16* __restrict__ Wqr,
                                                   u16* __restrict__ Wkr,
                                                   u16* __restrict__ Wvt,
                                                   float* __restrict__ sums) {
  const int id = blockIdx.x;
  const int tid = threadIdx.x;
  if (id == 5376) {                      // zero sums: 8192 floats
    f32x4 z = (f32x4)(0.0f);
#pragma unroll
    for (int i = 0; i < 8; ++i)
      *reinterpret_cast<f32x4*>(&sums[tid * 4 + i * 1024]) = z;
    return;
  }
  if (id < 5120) {
    const float* src;
    u16* dst;
    float scale = 1.0f;
    long i;
    if (id < 4096) {
      src = X; dst = Xb; i = ((long)id * 256 + tid) * 8;
    } else if (id < 4608) {
      src = Wq; dst = Wqr; scale = 1.0f / 32.0f;   // fold 1/sqrt(1024)
      i = ((long)(id - 4096) * 256 + tid) * 8;
    } else {
      src = Wk; dst = Wkr;
      i = ((long)(id - 4608) * 256 + tid) * 8;
    }
    float4 a = *reinterpret_cast<const float4*>(src + i);
    float4 b = *reinterpret_cast<const float4*>(src + i + 4);
    u16x8 o;
    o[0] = f2bf(a.x * scale); o[1] = f2bf(a.y * scale);
    o[2] = f2bf(a.z * scale); o[3] = f2bf(a.w * scale);
    o[4] = f2bf(b.x * scale); o[5] = f2bf(b.y * scale);
    o[6] = f2bf(b.z * scale); o[7] = f2bf(b.w * scale);
    *reinterpret_cast<u16x8*>(dst + i) = o;
    return;
  }
  // Wv transpose: Wvt[c*1024 + r] = Wv[r][c]
  __shared__ u16 t[64][72];
  const int id2 = id - 5120;          // 0..255
  const int c0 = (id2 & 15) * 64;
  const int r0 = (id2 >> 4) * 64;
#pragma unroll
  for (int i = 0; i < 4; ++i) {
    int slot = tid + 256 * i;
    int lr = slot >> 4;
    int lc4 = slot & 15;
    float4 v = *reinterpret_cast<const float4*>(Wv + (long)(r0 + lr) * 1024 + c0 + lc4 * 4);
    t[lr][lc4 * 4 + 0] = f2bf(v.x);
    t[lr][lc4 * 4 + 1] = f2bf(v.y);
    t[lr][lc4 * 4 + 2] = f2bf(v.z);
    t[lr][lc4 * 4 + 3] = f2bf(v.w);
  }
  __syncthreads();
#pragma unroll
  for (int i = 0; i < 2; ++i) {
    int slot = tid + 256 * i;
    int orow = slot >> 3;
    int oc = slot & 7;
    u16x8 o;
#pragma unroll
    for (int j = 0; j < 8; ++j) o[j] = t[oc * 8 + j][orow];
    *reinterpret_cast<u16x8*>(Wvt + (long)(c0 + orow) * 1024 + r0 + oc * 8) = o;
  }
}

// ---------------- G: Gt = NT(Wkr, Wqr), 128x128, 4 waves (unchanged) ----------
__global__ __launch_bounds__(256, 2) void gemm_g(const u16* __restrict__ A,
                                                 const u16* __restrict__ B,
                                                 u16* __restrict__ Gt) {
  const int bm = blockIdx.x >> 3;       // 0..7
  const int bn = blockIdx.x & 7;
  const int m0 = bm * 128, n0 = bn * 128;
  const int K = 1024;

  __shared__ u16 ldsA[2][8192];
  __shared__ u16 ldsB[2][8192];

  const int tid = threadIdx.x;
  const int lane = tid & 63;
  const int wid = tid >> 6;
  const int wm = wid >> 1, wn = wid & 1;
  const int l16 = lane & 15, lh = lane >> 4;
  const int srow = lane >> 3;
  const int scol = ((lane & 7) ^ srow) * 8;  // pre-swizzled source column
  const int rsw = l16 & 7;                   // read-side swizzle key

  f32x4 acc[4][4];
#pragma unroll
  for (int mi = 0; mi < 4; ++mi)
#pragma unroll
    for (int ni = 0; ni < 4; ++ni) acc[mi][ni] = (f32x4)(0.0f);

  auto stage = [&](int d, int k0) {
#pragma unroll
    for (int s = 0; s < 4; ++s) {
      const int seg = wid * 4 + s;           // 0..15 (1KB segments)
      const int row = seg * 8 + srow;        // 0..127
      gload_lds16(A + (long)(m0 + row) * K + k0 + scol, &ldsA[d][seg * 512]);
      gload_lds16(B + (long)(n0 + row) * K + k0 + scol, &ldsB[d][seg * 512]);
    }
  };

  stage(0, 0);
  int cur = 0;
  for (int k0 = 0; k0 < K; k0 += 64) {
    __syncthreads();
    if (k0 + 64 < K) stage(cur ^ 1, k0 + 64);
#pragma unroll
    for (int kk = 0; kk < 2; ++kk) {
      bf16x8 af[4], bfr[4];
#pragma unroll
      for (int mi = 0; mi < 4; ++mi)
        af[mi] = *reinterpret_cast<const bf16x8*>(
            &ldsA[cur][(wm * 64 + mi * 16 + l16) * 64 + (((kk * 4 + lh) ^ rsw)) * 8]);
#pragma unroll
      for (int ni = 0; ni < 4; ++ni)
        bfr[ni] = *reinterpret_cast<const bf16x8*>(
            &ldsB[cur][(wn * 64 + ni * 16 + l16) * 64 + (((kk * 4 + lh) ^ rsw)) * 8]);
#pragma unroll
      for (int mi = 0; mi < 4; ++mi)
#pragma unroll
        for (int ni = 0; ni < 4; ++ni)
          acc[mi][ni] = __builtin_amdgcn_mfma_f32_16x16x32_bf16(bfr[ni], af[mi], acc[mi][ni], 0, 0, 0);
    }
    cur ^= 1;
  }

  // Swapped: Gt[m0+wm*64+mi*16+l16][n0+wn*64+ni*16+lh*4+r]
  const long rown = (long)(m0 + wm * 64 + l16);
  const int coln = n0 + wn * 64 + lh * 4;
#pragma unroll
  for (int mi = 0; mi < 4; ++mi)
#pragma unroll
    for (int ni = 0; ni < 4; ++ni) {
      u16x4 o;
#pragma unroll
      for (int r = 0; r < 4; ++r) o[r] = f2bf(acc[mi][ni][r]);
      *reinterpret_cast<u16x4*>(&Gt[(rown + mi * 16) * 1024 + coln + ni * 16]) = o;
    }
}

// ---------------- [T1|V] = NT(Xb, [Gt;Wvt]): 128x128, 8 waves (r18, unchanged) ----
__global__ __launch_bounds__(512, 2) void gemm_t1v(const u16* __restrict__ Xb,
                                                   const u16* __restrict__ WG,
                                                   u16* __restrict__ T1,
                                                   u16* __restrict__ Vt) {
  const int id = blockIdx.x;            // 0..1023
  const int xcd = id & 7, j = id >> 3;  // j: 0..127
  const int bn = (xcd & 1) * 8 + (j & 7);        // 0..15
  const int bm = ((xcd >> 1) << 4) + (j >> 3);   // 0..63
  const int m0 = bm * 128, n0 = bn * 128;
  const int K = 1024;

  __shared__ u16 ldsA[2][8192];
  __shared__ u16 ldsB[2][8192];

  const int tid = threadIdx.x;          // 0..511
  const int lane = tid & 63;
  const int wid = tid >> 6;             // 0..7
  const int wm = wid >> 2, wn = wid & 3;
  const int l16 = lane & 15, lh = lane >> 4;
  const int strow = tid >> 3;                       // 0..63
  const int scol = ((tid & 7) ^ (strow & 7)) * 8;   // pre-swizzled source col
  const int rsw = l16 & 7;                          // read-side swizzle key

  const bool vblk = (bn >= 8);

  f32x4 acc[4][2];
#pragma unroll
  for (int mi = 0; mi < 4; ++mi)
#pragma unroll
    for (int ni = 0; ni < 2; ++ni) acc[mi][ni] = (f32x4)(0.0f);

  auto stage = [&](int d, int k0) {
#pragma unroll
    for (int l = 0; l < 2; ++l) {
      const int row = l * 64 + strow;   // 0..127
      gload_lds16(Xb + (long)(m0 + row) * K + k0 + scol, &ldsA[d][l * 4096 + tid * 8]);
      gload_lds16(WG + (long)(n0 + row) * K + k0 + scol, &ldsB[d][l * 4096 + tid * 8]);
    }
  };

  stage(0, 0);
  int cur = 0;
  for (int k0 = 0; k0 < K; k0 += 64) {
    __syncthreads();                          // buf[cur] ready; old readers done
    if (k0 + 64 < K) stage(cur ^ 1, k0 + 64); // lands during compute below
#pragma unroll
    for (int kk = 0; kk < 2; ++kk) {
      bf16x8 af[4], bfr[2];
#pragma unroll
      for (int mi = 0; mi < 4; ++mi)
        af[mi] = *reinterpret_cast<const bf16x8*>(
            &ldsA[cur][(wm * 64 + mi * 16 + l16) * 64 + (((kk * 4 + lh) ^ rsw)) * 8]);
#pragma unroll
      for (int ni = 0; ni < 2; ++ni)
        bfr[ni] = *reinterpret_cast<const bf16x8*>(
            &ldsB[cur][(wn * 32 + ni * 16 + l16) * 64 + (((kk * 4 + lh) ^ rsw)) * 8]);
      if (!vblk) {
#pragma unroll
        for (int mi = 0; mi < 4; ++mi)
#pragma unroll
          for (int ni = 0; ni < 2; ++ni)
            acc[mi][ni] = __builtin_amdgcn_mfma_f32_16x16x32_bf16(bfr[ni], af[mi], acc[mi][ni], 0, 0, 0);
      } else {
#pragma unroll
        for (int mi = 0; mi < 4; ++mi)
#pragma unroll
          for (int ni = 0; ni < 2; ++ni)
            acc[mi][ni] = __builtin_amdgcn_mfma_f32_16x16x32_bf16(af[mi], bfr[ni], acc[mi][ni], 0, 0, 0);
      }
    }
    cur ^= 1;
  }

  if (!vblk) {
    // Swapped: T1[m0+wm*64+mi*16+l16][bn*128+wn*32+ni*16+lh*4+r]
    const long rown = (long)(m0 + wm * 64 + l16);
    const int coln = bn * 128 + wn * 32 + lh * 4;
#pragma unroll
    for (int mi = 0; mi < 4; ++mi)
#pragma unroll
      for (int ni = 0; ni < 2; ++ni) {
        u16x4 o;
#pragma unroll
        for (int r = 0; r < 4; ++r) o[r] = f2bf(acc[mi][ni][r]);
        *reinterpret_cast<u16x4*>(&T1[(rown + mi * 16) * 1024 + coln + ni * 16]) = o;
      }
  } else {
    // V (normal order): D row = M-dim(t). Vt[b][e][t], vector along t.
    const int b = m0 >> 11;
    const int t0 = (m0 & 2047) + wm * 64 + lh * 4;
    const int e0 = (bn - 8) * 128 + wn * 32 + l16;
#pragma unroll
    for (int mi = 0; mi < 4; ++mi)
#pragma unroll
      for (int ni = 0; ni < 2; ++ni) {
        u16x4 o;
#pragma unroll
        for (int r = 0; r < 4; ++r) o[r] = f2bf(acc[mi][ni][r]);
        *reinterpret_cast<u16x4*>(
            &Vt[(long)b * 2097152 + (long)(e0 + ni * 16) * 2048 + t0 + mi * 16]) = o;
      }
  }
}

// ---------------- S = exp(T1 X^T): 64x128 tiles, BK=64, 4/CU (r18, unchanged) -----
__global__ __launch_bounds__(256, 4) void gemm_s(const u16* __restrict__ T1,
                                                 const u16* __restrict__ Xb,
                                                 u16* __restrict__ Sg,
                                                 float* __restrict__ Sums) {
  const int id = blockIdx.x;            // 0..1087
  const int x = id & 7;                 // XCD (round-robin assumption)
  const int q = id >> 3;                // 0..135
  const int bz = q / 34;
  int u = q - bz * 34;
  int qr, kc;
  const int n1 = 32 - 2 * x;            // tiles with kc = x  (qr = 2x..31)
  if (u < n1) { kc = x;      qr = 2 * x + u; }
  else        { kc = 15 - x; qr = 30 - 2 * x + (u - n1); }
  const int m0 = qr * 64, n0 = kc * 128;
  const int K = 1024;

  const u16* A = T1 + (long)bz * 2097152;
  const u16* B = Xb + (long)bz * 2097152;

  __shared__ u16 ldsA[2][4096];    // 64 x 64
  __shared__ u16 ldsB[2][8192];    // 128 x 64

  const int tid = threadIdx.x;          // 0..255
  const int lane = tid & 63;
  const int wn = tid >> 6;              // wave 0..3 owns cols wn*32..wn*32+31
  const int l16 = lane & 15, lh = lane >> 4;
  const int strow = tid >> 3;                       // 0..31
  const int scol = ((tid & 7) ^ (strow & 7)) * 8;   // pre-swizzled source col
  const int rsw = l16 & 7;                          // read-side swizzle key

  f32x4 acc[4][2];
#pragma unroll
  for (int mi = 0; mi < 4; ++mi)
#pragma unroll
    for (int ni = 0; ni < 2; ++ni) acc[mi][ni] = (f32x4)(0.0f);

  auto stage = [&](int d, int k0) {
#pragma unroll
    for (int l = 0; l < 2; ++l)
      gload_lds16(A + (long)(m0 + l * 32 + strow) * K + k0 + scol,
                  &ldsA[d][l * 2048 + tid * 8]);
#pragma unroll
    for (int l = 0; l < 4; ++l)
      gload_lds16(B + (long)(n0 + l * 32 + strow) * K + k0 + scol,
                  &ldsB[d][l * 2048 + tid * 8]);
  };

  stage(0, 0);
  int cur = 0;
  for (int k0 = 0; k0 < K; k0 += 64) {
    __syncthreads();
    if (k0 + 64 < K) stage(cur ^ 1, k0 + 64);
#pragma unroll
    for (int kk = 0; kk < 2; ++kk) {
      bf16x8 af[4], bfr[2];
#pragma unroll
      for (int mi = 0; mi < 4; ++mi)
        af[mi] = *reinterpret_cast<const bf16x8*>(
            &ldsA[cur][(mi * 16 + l16) * 64 + (((kk * 4 + lh) ^ rsw)) * 8]);
#pragma unroll
      for (int ni = 0; ni < 2; ++ni)
        bfr[ni] = *reinterpret_cast<const bf16x8*>(
            &ldsB[cur][(wn * 32 + ni * 16 + l16) * 64 + (((kk * 4 + lh) ^ rsw)) * 8]);
#pragma unroll
      for (int mi = 0; mi < 4; ++mi)
#pragma unroll
        for (int ni = 0; ni < 2; ++ni)
          acc[mi][ni] = __builtin_amdgcn_mfma_f32_16x16x32_bf16(bfr[ni], af[mi], acc[mi][ni], 0, 0, 0);
    }
    cur ^= 1;
  }

  // P = exp(S), zero above diagonal; row sums from bf16-rounded values.
  u16* C = Sg + (long)bz * 4194304;
  float* sums = Sums + (long)bz * 2048;
  const int coln = n0 + wn * 32 + lh * 4;
#pragma unroll
  for (int mi = 0; mi < 4; ++mi) {
    const int gr = m0 + mi * 16 + l16;
    float rs = 0.0f;
#pragma unroll
    for (int ni = 0; ni < 2; ++ni) {
      u16x4 o;
#pragma unroll
      for (int r = 0; r < 4; ++r) {
        const int gc = coln + ni * 16 + r;
        const float e = (gc <= gr) ? __expf(acc[mi][ni][r]) : 0.0f;
        const u16 ub = f2bf(e);
        o[r] = ub;
        rs += bf2f(ub);
      }
      *reinterpret_cast<u16x4*>(&C[(long)gr * 2048 + coln + ni * 16]) = o;
    }
    rs += __shfl_xor(rs, 16);
    rs += __shfl_xor(rs, 32);
    if (lh == 0) atomicAdd(&sums[gr], rs);
  }
}

// ---------------- PV GEMM: 128x128, 8 waves, balanced pairing (unchanged) ----
__global__ __launch_bounds__(512, 2) void gemm_pv(const u16* __restrict__ Ag,
                                                  const u16* __restrict__ Bg,
                                                  float* __restrict__ Cg,
                                                  const float* __restrict__ Sums) {
  const int id = blockIdx.x;            // 0..511
  const int x = id & 7;                 // XCD; also bn
  const int q = id >> 3;                // 0..63
  const int f = (q ^ (q >> 5)) & 1;
  const int i5 = ((q >> 1) & 15) | (((q >> 5) & 1) << 4);
  const int bmb = i5 & 7;
  const int bz = (i5 >> 3) & 3;
  const int bm = f ? (15 - bmb) : bmb;
  const int bn = x;
  const int K = 2048;

  const u16* A = Ag + (long)bz * 4194304;
  const u16* B = Bg + (long)bz * 2097152;
  const int m0 = bm * 128, n0 = bn * 128;
  const int kEnd = m0 + 128;

  __shared__ u16 ldsA[2][8192];
  __shared__ u16 ldsB[2][8192];

  const int tid = threadIdx.x;          // 0..511
  const int lane = tid & 63;
  const int wid = tid >> 6;             // 0..7
  const int wm = wid >> 2, wn = wid & 3;
  const int l16 = lane & 15, lh = lane >> 4;
  const int strow = tid >> 3;                       // 0..63
  const int scol = ((tid & 7) ^ (strow & 7)) * 8;   // pre-swizzled source column
  const int rsw = l16 & 7;                          // read-side swizzle key

  f32x4 acc[4][2];
#pragma unroll
  for (int mi = 0; mi < 4; ++mi)
#pragma unroll
    for (int ni = 0; ni < 2; ++ni) acc[mi][ni] = (f32x4)(0.0f);

  auto stage = [&](int d, int k0) {
#pragma unroll
    for (int l = 0; l < 2; ++l) {
      const int row = l * 64 + strow;   // 0..127
      gload_lds16(A + (long)(m0 + row) * K + k0 + scol, &ldsA[d][l * 4096 + tid * 8]);
      gload_lds16(B + (long)(n0 + row) * K + k0 + scol, &ldsB[d][l * 4096 + tid * 8]);
    }
  };

  stage(0, 0);
  int cur = 0;
  for (int k0 = 0; k0 < kEnd; k0 += 64) {
    __syncthreads();
    if (k0 + 64 < kEnd) stage(cur ^ 1, k0 + 64);
#pragma unroll
    for (int kk = 0; kk < 2; ++kk) {
      bf16x8 af[4], bfr[2];
#pragma unroll
      for (int mi = 0; mi < 4; ++mi)
        af[mi] = *reinterpret_cast<const bf16x8*>(
            &ldsA[cur][(wm * 64 + mi * 16 + l16) * 64 + (((kk * 4 + lh) ^ rsw)) * 8]);
#pragma unroll
      for (int ni = 0; ni < 2; ++ni)
        bfr[ni] = *reinterpret_cast<const bf16x8*>(
            &ldsB[cur][(wn * 32 + ni * 16 + l16) * 64 + (((kk * 4 + lh) ^ rsw)) * 8]);
#pragma unroll
      for (int mi = 0; mi < 4; ++mi)
#pragma unroll
        for (int ni = 0; ni < 2; ++ni)
          acc[mi][ni] = __builtin_amdgcn_mfma_f32_16x16x32_bf16(bfr[ni], af[mi], acc[mi][ni], 0, 0, 0);
    }
    cur ^= 1;
  }

  // O = acc / rowsum
  float* C = Cg + (long)bz * 2097152;
  const float* sums = Sums + (long)bz * 2048;
  const long rown = (long)(m0 + wm * 64 + l16);
  const int coln = n0 + wn * 32 + lh * 4;
#pragma unroll
  for (int mi = 0; mi < 4; ++mi) {
    const float inv = 1.0f / sums[(int)rown + mi * 16];
#pragma unroll
    for (int ni = 0; ni < 2; ++ni) {
      f32x4 v = acc[mi][ni] * inv;
      *reinterpret_cast<f32x4*>(&C[(rown + mi * 16) * 1024 + coln + ni * 16]) = v;
    }
  }
}

extern "C" void kernel_launch(void* const* d_in, const int* in_sizes, int n_in,
                              void* d_out, int out_size, void* d_ws, size_t ws_size,
                              hipStream_t stream) {
  const float* X  = (const float*)d_in[0];
  const float* Wq = (const float*)d_in[1];
  const float* Wk = (const float*)d_in[2];
  const float* Wv = (const float*)d_in[3];

  // workspace layout (u16 elements)
  u16* Xb  = (u16*)d_ws;                // 8192*1024
  u16* Wqr = Xb + 8388608;              // 1M, row-major Wq*(1/32)
  u16* Wkr = Wqr + 1048576;             // 1M, row-major Wk
  u16* WG  = Wkr + 1048576;             // [Gt; Wvt] (2M) — contiguous B for T1V
  u16* T1  = WG + 2097152;              // 8192*1024
  u16* Vt  = T1 + 8388608;              // [b][1024][2048]
  u16* S   = Vt + 8388608;              // [b][2048][2048] -> holds P = exp(scores)
  float* sums = (float*)(S + 16777216); // [b][2048] row sums (32 KB)

  // cast X, Wq (scaled), Wk row-major; transpose Wv; zero sums (one dispatch)
  prep_kernel<<<5377, 256, 0, stream>>>(X, Wq, Wk, Wv, Xb, Wqr, Wkr,
                                        WG + 1048576, sums);

  // Gt = NT(Wkr, Wqr): Gt[d'][d] = M[d,d'] — 2.1 GF, proven dbuf kernel
  gemm_g<<<64, 256, 0, stream>>>(Wkr, Wqr, WG);

  // [T1 | V] = NT(Xb, [Gt; Wvt]) — 128x128, 8 waves, 1024 blocks = 2 rounds
  gemm_t1v<<<1024, 512, 0, stream>>>(Xb, WG, T1, Vt);

  // P = exp(T1 X^T) per batch (causal zeros; row sums via atomics), 4/CU
  gemm_s<<<1088, 256, 0, stream>>>(T1, Xb, S, sums);

  // O = P V / rowsum
  gemm_pv<<<512, 512, 0, stream>>>(S, Vt, (float*)d_out, sums);
}